// Round 13
// baseline (251.618 us; speedup 1.0000x reference)
//
#include <hip/hip_runtime.h>
#include <hip/hip_bf16.h>

#define NN 100000
#define NE 1000000
#define DIN 64
#define DH 128
#define NB 98        // dst-buckets of 1024 nodes
#define CAP 16384    // fixed slots per bucket (max expected ~10.7k)
#define NTILES 1563  // ceil(NN/64)
#define EDGEB 256    // blocks doing edge-bucket role
#define CVTB 3125    // blocks doing convert role (NN*DIN/8 / 256)

typedef __attribute__((ext_vector_type(8))) short short8;
typedef __attribute__((ext_vector_type(4))) float floatx4;

// ---- workspace layout (32-bit words) ----
// bnsum[128]|bnsq[128] | gcur[98]+pad | offs[NN+1]+pad | csr[NE] | plr[NN*4] |
// wfrag[8192] | xb[NN*32] | hb[NN*64 bf16]
// ebuf (packed int, NB*CAP = 1.6M words) overlays the hb region (disjoint lifetime).
#define OFF_BN    0
#define OFF_GCUR  256
#define OFF_OFFS  384
#define OFF_CSR   (OFF_OFFS + NN + 4)
#define OFF_PLR   (OFF_CSR + NE)
#define OFF_WF    (OFF_PLR + NN * 4)
#define OFF_XB    (OFF_WF + 8192)
#define OFF_H     (OFF_XB + NN * 32)

static __device__ __forceinline__ float b2f(short s) {
    union { unsigned u; float f; } c;
    c.u = ((unsigned)(unsigned short)s) << 16;
    return c.f;
}

// ------- fused: edge bucketing (blocks 0..255) + x->bf16 / wfrag (blocks 256+) -------
__global__ __launch_bounds__(256) void k_bucketprep(const float* __restrict__ x,
                                                    const float* __restrict__ W1l,
                                                    const float* __restrict__ W1r,
                                                    const int* __restrict__ src,
                                                    const int* __restrict__ dst,
                                                    ushort* __restrict__ xb,
                                                    ushort* __restrict__ wfrag,
                                                    int* __restrict__ gcur,
                                                    int* __restrict__ ebuf) {
    const int bid = blockIdx.x;
    const int tid = threadIdx.x;
    if (bid < EDGEB) {
        // edge role: per-block LDS counts -> contiguous claim on gcur[b] -> packed scatter
        __shared__ int lh[NB], lb[NB];
        const int per = (NE + EDGEB - 1) / EDGEB;
        const int e0 = bid * per, e1 = min(e0 + per, NE);
        if (tid < NB) lh[tid] = 0;
        __syncthreads();
        for (int e = e0 + tid; e < e1; e += 256)
            atomicAdd(&lh[dst[e] >> 10], 1);
        __syncthreads();
        if (tid < NB) { lb[tid] = atomicAdd(&gcur[tid], lh[tid]); lh[tid] = 0; }
        __syncthreads();
        for (int e = e0 + tid; e < e1; e += 256) {
            int d = dst[e];
            int b = d >> 10;
            int slot = b * CAP + lb[b] + atomicAdd(&lh[b], 1);
            ebuf[slot] = (src[e] << 10) | (d & 1023);  // pack: src(17b) | dstLocal(10b)
        }
    } else {
        int t = (bid - EDGEB) * 256 + tid;
        if (t < NN * DIN / 8) {
            float4 a = *(const float4*)(x + (size_t)t * 8);
            float4 b = *(const float4*)(x + (size_t)t * 8 + 4);
            __hip_bfloat16 o[8];
            o[0] = __float2bfloat16(a.x); o[1] = __float2bfloat16(a.y);
            o[2] = __float2bfloat16(a.z); o[3] = __float2bfloat16(a.w);
            o[4] = __float2bfloat16(b.x); o[5] = __float2bfloat16(b.y);
            o[6] = __float2bfloat16(b.z); o[7] = __float2bfloat16(b.w);
            *(uint4*)&xb[(size_t)t * 8] = *(uint4*)o;
        }
        if (t < 2048) {  // wfrag[((ct*4+ks)*64+l)*8+j] = Wcat[ks*32+(l>>4)*8+j][ct*16+(l&15)]
            int ct = t >> 8, ks = (t >> 6) & 3, l = t & 63;
            int k0 = ks * 32 + (l >> 4) * 8;
            int col = ct * 16 + (l & 15);
            ushort o[8];
#pragma unroll
            for (int j = 0; j < 8; ++j) {
                int k = k0 + j;
                float v = (k < 64) ? W1l[k * DH + col] : W1r[(k - 64) * DH + col];
                __hip_bfloat16 b = __float2bfloat16(v);
                o[j] = *(ushort*)&b;
            }
            *(uint4*)&wfrag[(size_t)t * 8] = *(uint4*)o;
        }
    }
}

// ------- place: per-bucket node-histogram + scan -> offs + csr -------
__global__ __launch_bounds__(1024) void k_place(const int* __restrict__ ebuf,
                                                const int* __restrict__ gcur,
                                                int* __restrict__ offs,
                                                int* __restrict__ csr) {
    __shared__ int lcnt[1024], loff[1024], pre[NB];
    __shared__ int sbase;
    const int b = blockIdx.x;
    const int tid = threadIdx.x;
    const int nb0 = b << 10;
    const int node_n = min(1024, NN - nb0);
    if (tid < NB) pre[tid] = gcur[tid];  // parallel load of all bucket counts
    lcnt[tid] = 0;
    __syncthreads();
    if (tid == 0) {  // in-LDS prefix (98 adds)
        int acc = 0;
        for (int j = 0; j < b; ++j) acc += pre[j];
        sbase = acc;
    }
    const int e0 = b * CAP;
    const int ecnt = pre[b];
    for (int i = tid; i < ecnt; i += 1024)
        atomicAdd(&lcnt[ebuf[e0 + i] & 1023], 1);
    __syncthreads();
    // Hillis-Steele scan of lcnt -> exclusive prefix
    int v = lcnt[tid];
    int sum = v;
    loff[tid] = sum;
    __syncthreads();
    for (int off = 1; off < 1024; off <<= 1) {
        int o = (tid >= off) ? loff[tid - off] : 0;
        __syncthreads();
        sum += o;
        loff[tid] = sum;
        __syncthreads();
    }
    const int excl = sum - v;
    const int base = sbase;
    if (tid < node_n) offs[nb0 + tid] = base + excl;
    if (b == NB - 1 && tid == 0) offs[NN] = NE;
    lcnt[tid] = 0;
    loff[tid] = excl;
    __syncthreads();
    for (int i = tid; i < ecnt; i += 1024) {
        int e = ebuf[e0 + i];
        int d = e & 1023;
        int slot = base + loff[d] + atomicAdd(&lcnt[d], 1);
        csr[slot] = e >> 10;
    }
}

// ------- fused aggregate + MFMA dual-GEMM: one block per 64-node tile -------
// Phase A: stage own-x rows into sA cols 64..127; wave w gather-means nodes
//          [tb+16w, tb+16w+16) into sA cols 0..63 (16B/lane vectorized gather).
// Phase B: hb = bf16([agg|x] @ [W1l;W1r] + b1) via MFMA, BN partials in regs.
__global__ __launch_bounds__(256, 4) void k_aggmm(const ushort* __restrict__ xb,
                                                  const int* __restrict__ offs,
                                                  const int* __restrict__ csr,
                                                  const ushort* __restrict__ wfrag,
                                                  const float* __restrict__ b1,
                                                  ushort* __restrict__ hb,
                                                  float* __restrict__ bnsum,
                                                  float* __restrict__ bnsq) {
    __shared__ ushort sA[64 * 136];  // 17 KB, padded stride 136
    const int tid = threadIdx.x;
    const int l = tid & 63, w = tid >> 6;
    const int r0 = l & 15, kg = l >> 4;
    const int g = l >> 3, d8 = l & 7;
    const int tb = blockIdx.x * 64;

    short8 bf[2][4];
#pragma unroll
    for (int c = 0; c < 2; ++c)
#pragma unroll
        for (int ks = 0; ks < 4; ++ks)
            bf[c][ks] = *(const short8*)&wfrag[(((2 * w + c) * 4 + ks) * 64 + l) * 8];

    float bias2[2];
    bias2[0] = b1[(2 * w) * 16 + r0];
    bias2[1] = b1[(2 * w + 1) * 16 + r0];

    // stage own-x rows (cols 64..127): 512 chunks of 16B
#pragma unroll
    for (int i = 0; i < 2; ++i) {
        int f = tid + i * 256;  // 0..511
        int row = f >> 3, c8 = f & 7;
        *(uint4*)&sA[row * 136 + 64 + c8 * 8] =
            *(const uint4*)&xb[(size_t)(tb + row) * DIN + c8 * 8];
    }

    // gather-mean: wave w handles 16 nodes sequentially (2-way interleaved)
#pragma unroll 2
    for (int nn = 0; nn < 16; ++nn) {
        int node = tb + w * 16 + nn;
        float a[8] = {0, 0, 0, 0, 0, 0, 0, 0};
        int deg = 0;
        if (node < NN) {  // wave-uniform
            int beg = offs[node];
            deg = offs[node + 1] - beg;
            for (int ch = 0; ch < deg; ch += 8) {
                int j = ch + g;
                if (j < deg) {
                    int sv = csr[beg + j];
                    short8 v = *(const short8*)&xb[(size_t)sv * DIN + d8 * 8];
#pragma unroll
                    for (int i = 0; i < 8; ++i) a[i] += b2f(v[i]);
                }
            }
        }
#pragma unroll
        for (int i = 0; i < 8; ++i) {
            a[i] += __shfl_xor(a[i], 8);
            a[i] += __shfl_xor(a[i], 16);
            a[i] += __shfl_xor(a[i], 32);
        }
        if (g == 0) {  // lanes 0..7 write the bf16 mean, 128B contiguous row
            float inv = 1.f / fmaxf((float)deg, 1.f);
            ushort o[8];
#pragma unroll
            for (int i = 0; i < 8; ++i) {
                __hip_bfloat16 b = __float2bfloat16(a[i] * inv);
                o[i] = *(ushort*)&b;
            }
            *(uint4*)&sA[(w * 16 + nn) * 136 + d8 * 8] = *(uint4*)o;
        }
    }
    __syncthreads();

    float psum2[2] = {0.f, 0.f}, psq2[2] = {0.f, 0.f};
#pragma unroll
    for (int s = 0; s < 4; ++s) {
        short8 af[4];
        const int abase = (s * 16 + r0) * 136 + kg * 8;
#pragma unroll
        for (int ks = 0; ks < 4; ++ks)
            af[ks] = *(const short8*)&sA[abase + ks * 32];
#pragma unroll
        for (int c = 0; c < 2; ++c) {
            floatx4 acc = {0.f, 0.f, 0.f, 0.f};
#pragma unroll
            for (int ks = 0; ks < 4; ++ks)
                acc = __builtin_amdgcn_mfma_f32_16x16x32_bf16(af[ks], bf[c][ks], acc, 0, 0, 0);
            const int col = (2 * w + c) * 16 + r0;
#pragma unroll
            for (int i = 0; i < 4; ++i) {
                int r = tb + s * 16 + kg * 4 + i;
                if (r < NN) {
                    float o = acc[i] + bias2[c];
                    __hip_bfloat16 ob = __float2bfloat16(o);
                    hb[(size_t)r * DH + col] = *(ushort*)&ob;
                    psum2[c] += o;
                    psq2[c] += o * o;
                }
            }
        }
    }

#pragma unroll
    for (int c = 0; c < 2; ++c) {
        float s = psum2[c], q = psq2[c];
        s += __shfl_xor(s, 16); s += __shfl_xor(s, 32);
        q += __shfl_xor(q, 16); q += __shfl_xor(q, 32);
        if (kg == 0) {  // lanes 0..15, channels disjoint across waves
            atomicAdd(&bnsum[(2 * w + c) * 16 + r0], s);
            atomicAdd(&bnsq[(2 * w + c) * 16 + r0], q);
        }
    }
}

// ---------------- per-node projection (BN affine computed per-block in LDS) ----------------
__global__ __launch_bounds__(256) void k_proj(const ushort* __restrict__ hb,
                                              const float* __restrict__ bnsum,
                                              const float* __restrict__ bnsq,
                                              const float* __restrict__ gamma,
                                              const float* __restrict__ beta,
                                              const float* __restrict__ W2l,
                                              const float* __restrict__ W2r,
                                              float4* __restrict__ plr) {
    __shared__ float sCA[DH], sCC[DH];
    int tid = threadIdx.x;
    if (tid < DH) {
        float mu = bnsum[tid] * (1.f / NN);
        float var = bnsq[tid] * (1.f / NN) - mu * mu;
        float a = rsqrtf(var + 1e-5f) * gamma[tid];
        sCA[tid] = a;
        sCC[tid] = beta[tid] - mu * a;
    }
    __syncthreads();
    int wid = (blockIdx.x * 256 + tid) >> 6;  // node
    int lane = tid & 63;
    if (wid >= NN) return;
    int c0 = lane * 2;
    uint hv = *(const uint*)&hb[(size_t)wid * DH + c0];
    float h0 = b2f((short)(hv & 0xffff));
    float h1 = b2f((short)(hv >> 16));
    float hb0 = fmaxf(h0 * sCA[c0] + sCC[c0], 0.f);
    float hb1 = fmaxf(h1 * sCA[c0 + 1] + sCC[c0 + 1], 0.f);
    float pl0 = hb0 * W2l[c0 * 2 + 0] + hb1 * W2l[c0 * 2 + 2];
    float pl1 = hb0 * W2l[c0 * 2 + 1] + hb1 * W2l[c0 * 2 + 3];
    float pr0 = hb0 * W2r[c0 * 2 + 0] + hb1 * W2r[c0 * 2 + 2];
    float pr1 = hb0 * W2r[c0 * 2 + 1] + hb1 * W2r[c0 * 2 + 3];
#pragma unroll
    for (int off = 32; off > 0; off >>= 1) {
        pl0 += __shfl_down(pl0, off);
        pl1 += __shfl_down(pl1, off);
        pr0 += __shfl_down(pr0, off);
        pr1 += __shfl_down(pr1, off);
    }
    if (lane == 0) plr[wid] = make_float4(pl0, pl1, pr0, pr1);
}

// ---------------- layer-2 aggregate + output (4-way unrolled gather) ----------------
__global__ __launch_bounds__(256) void k_out(const float4* __restrict__ plr,
                                             const int* __restrict__ offs,
                                             const int* __restrict__ csr,
                                             const float* __restrict__ b2,
                                             float* __restrict__ out) {
    int d = blockIdx.x * 256 + threadIdx.x;
    if (d >= NN) return;
    int beg = offs[d];
    int deg = offs[d + 1] - beg;
    const float2* pl2 = (const float2*)plr;
    float s0 = 0.f, s1 = 0.f;
    int i = 0;
    for (; i + 4 <= deg; i += 4) {
        int n0 = csr[beg + i], n1 = csr[beg + i + 1];
        int n2 = csr[beg + i + 2], n3 = csr[beg + i + 3];
        float2 p0 = pl2[(size_t)n0 * 2];
        float2 p1 = pl2[(size_t)n1 * 2];
        float2 p2 = pl2[(size_t)n2 * 2];
        float2 p3 = pl2[(size_t)n3 * 2];
        s0 += (p0.x + p1.x) + (p2.x + p3.x);
        s1 += (p0.y + p1.y) + (p2.y + p3.y);
    }
    for (; i < deg; ++i) {
        float2 p = pl2[(size_t)csr[beg + i] * 2];
        s0 += p.x;
        s1 += p.y;
    }
    float inv = 1.f / fmaxf((float)deg, 1.f);
    float4 me = plr[d];
    out[(size_t)d * 2 + 0] = s0 * inv + me.z + b2[0];
    out[(size_t)d * 2 + 1] = s1 * inv + me.w + b2[1];
}

extern "C" void kernel_launch(void* const* d_in, const int* in_sizes, int n_in,
                              void* d_out, int out_size, void* d_ws, size_t ws_size,
                              hipStream_t stream) {
    const float* x = (const float*)d_in[0];
    const int* ei = (const int*)d_in[1];
    const float* W1l = (const float*)d_in[2];
    const float* W1r = (const float*)d_in[3];
    const float* b1 = (const float*)d_in[4];
    const float* gamma = (const float*)d_in[5];
    const float* beta = (const float*)d_in[6];
    const float* W2l = (const float*)d_in[7];
    const float* W2r = (const float*)d_in[8];
    const float* b2 = (const float*)d_in[9];
    float* out = (float*)d_out;
    float* ws = (float*)d_ws;
    int* wsi = (int*)d_ws;

    const int* src = ei;
    const int* dst = ei + NE;

    float* bnsum = ws + OFF_BN;
    float* bnsq = ws + OFF_BN + 128;
    int* gcur = wsi + OFF_GCUR;
    int* offs = wsi + OFF_OFFS;
    int* csr = wsi + OFF_CSR;
    float4* plr = (float4*)(ws + OFF_PLR);
    ushort* wfrag = (ushort*)(ws + OFF_WF);
    ushort* xb = (ushort*)(ws + OFF_XB);
    ushort* hb = (ushort*)(ws + OFF_H);
    int* ebuf = (int*)(ws + OFF_H);  // overlays hb (dead before hb is written)

    // zero bn partials (256) + gcur (98) in one small memset (adjacent in layout)
    hipMemsetAsync(ws, 0, (256 + NB) * sizeof(float), stream);

    k_bucketprep<<<EDGEB + CVTB, 256, 0, stream>>>(x, W1l, W1r, src, dst, xb, wfrag, gcur, ebuf);
    k_place<<<NB, 1024, 0, stream>>>(ebuf, gcur, offs, csr);
    k_aggmm<<<NTILES, 256, 0, stream>>>(xb, offs, csr, wfrag, b1, hb, bnsum, bnsq);
    k_proj<<<(NN + 3) / 4, 256, 0, stream>>>(hb, bnsum, bnsq, gamma, beta, W2l, W2r, plr);
    k_out<<<(NN + 255) / 256, 256, 0, stream>>>(plr, offs, csr, b2, out);
}

// Round 14
// 224.481 us; speedup vs baseline: 1.1209x; 1.1209x over previous
//
#include <hip/hip_runtime.h>
#include <hip/hip_bf16.h>

#define NN 100000
#define NE 1000000
#define DIN 64
#define DH 128
#define NB 98        // dst-buckets of 1024 nodes
#define CAP 16384    // fixed slots per bucket (max expected ~10.7k)
#define NTILES 1563  // ceil(NN/64)
#define EDGEB 256    // blocks doing edge-bucket role
#define CVTB 3125    // blocks doing convert role (NN*DIN/8 / 256)

typedef __attribute__((ext_vector_type(8))) short short8;
typedef __attribute__((ext_vector_type(4))) float floatx4;

// ---- workspace layout (32-bit words) ----
// bnsum[128]|bnsq[128] | gcur[98]+pad | offs[NN+1]+pad | csr[NE] | plr[NN*4] |
// wfrag[8192] | aggb16[NN*32] | xb[NN*32] | hb[NN*64 bf16]
// ebuf (packed int, NB*CAP = 1.6M words) overlays the hb region (disjoint lifetime).
#define OFF_BN    0
#define OFF_GCUR  256
#define OFF_OFFS  384
#define OFF_CSR   (OFF_OFFS + NN + 4)
#define OFF_PLR   (OFF_CSR + NE)
#define OFF_WF    (OFF_PLR + NN * 4)
#define OFF_AGB   (OFF_WF + 8192)
#define OFF_XB    (OFF_AGB + NN * 32)
#define OFF_H     (OFF_XB + NN * 32)

static __device__ __forceinline__ float b2f(short s) {
    union { unsigned u; float f; } c;
    c.u = ((unsigned)(unsigned short)s) << 16;
    return c.f;
}

// ------- fused: edge bucketing (blocks 0..255) + x->bf16 / wfrag (blocks 256+) -------
__global__ __launch_bounds__(256) void k_bucketprep(const float* __restrict__ x,
                                                    const float* __restrict__ W1l,
                                                    const float* __restrict__ W1r,
                                                    const int* __restrict__ src,
                                                    const int* __restrict__ dst,
                                                    ushort* __restrict__ xb,
                                                    ushort* __restrict__ wfrag,
                                                    int* __restrict__ gcur,
                                                    int* __restrict__ ebuf) {
    const int bid = blockIdx.x;
    const int tid = threadIdx.x;
    if (bid < EDGEB) {
        // edge role: per-block LDS counts -> contiguous claim on gcur[b] -> packed scatter
        __shared__ int lh[NB], lb[NB];
        const int per = (NE + EDGEB - 1) / EDGEB;
        const int e0 = bid * per, e1 = min(e0 + per, NE);
        if (tid < NB) lh[tid] = 0;
        __syncthreads();
        for (int e = e0 + tid; e < e1; e += 256)
            atomicAdd(&lh[dst[e] >> 10], 1);
        __syncthreads();
        if (tid < NB) { lb[tid] = atomicAdd(&gcur[tid], lh[tid]); lh[tid] = 0; }
        __syncthreads();
        for (int e = e0 + tid; e < e1; e += 256) {
            int d = dst[e];
            int b = d >> 10;
            int slot = b * CAP + lb[b] + atomicAdd(&lh[b], 1);
            ebuf[slot] = (src[e] << 10) | (d & 1023);  // pack: src(17b) | dstLocal(10b)
        }
    } else {
        int t = (bid - EDGEB) * 256 + tid;
        if (t < NN * DIN / 8) {
            float4 a = *(const float4*)(x + (size_t)t * 8);
            float4 b = *(const float4*)(x + (size_t)t * 8 + 4);
            __hip_bfloat16 o[8];
            o[0] = __float2bfloat16(a.x); o[1] = __float2bfloat16(a.y);
            o[2] = __float2bfloat16(a.z); o[3] = __float2bfloat16(a.w);
            o[4] = __float2bfloat16(b.x); o[5] = __float2bfloat16(b.y);
            o[6] = __float2bfloat16(b.z); o[7] = __float2bfloat16(b.w);
            *(uint4*)&xb[(size_t)t * 8] = *(uint4*)o;
        }
        if (t < 2048) {  // wfrag[((ct*4+ks)*64+l)*8+j] = Wcat[ks*32+(l>>4)*8+j][ct*16+(l&15)]
            int ct = t >> 8, ks = (t >> 6) & 3, l = t & 63;
            int k0 = ks * 32 + (l >> 4) * 8;
            int col = ct * 16 + (l & 15);
            ushort o[8];
#pragma unroll
            for (int j = 0; j < 8; ++j) {
                int k = k0 + j;
                float v = (k < 64) ? W1l[k * DH + col] : W1r[(k - 64) * DH + col];
                __hip_bfloat16 b = __float2bfloat16(v);
                o[j] = *(ushort*)&b;
            }
            *(uint4*)&wfrag[(size_t)t * 8] = *(uint4*)o;
        }
    }
}

// ------- place: per-bucket node-histogram + scan -> offs + csr -------
__global__ __launch_bounds__(1024) void k_place(const int* __restrict__ ebuf,
                                                const int* __restrict__ gcur,
                                                int* __restrict__ offs,
                                                int* __restrict__ csr) {
    __shared__ int lcnt[1024], loff[1024], pre[NB];
    __shared__ int sbase;
    const int b = blockIdx.x;
    const int tid = threadIdx.x;
    const int nb0 = b << 10;
    const int node_n = min(1024, NN - nb0);
    if (tid < NB) pre[tid] = gcur[tid];  // parallel load of all bucket counts
    lcnt[tid] = 0;
    __syncthreads();
    if (tid == 0) {  // in-LDS prefix (98 adds)
        int acc = 0;
        for (int j = 0; j < b; ++j) acc += pre[j];
        sbase = acc;
    }
    const int e0 = b * CAP;
    const int ecnt = pre[b];
    for (int i = tid; i < ecnt; i += 1024)
        atomicAdd(&lcnt[ebuf[e0 + i] & 1023], 1);
    __syncthreads();
    // Hillis-Steele scan of lcnt -> exclusive prefix
    int v = lcnt[tid];
    int sum = v;
    loff[tid] = sum;
    __syncthreads();
    for (int off = 1; off < 1024; off <<= 1) {
        int o = (tid >= off) ? loff[tid - off] : 0;
        __syncthreads();
        sum += o;
        loff[tid] = sum;
        __syncthreads();
    }
    const int excl = sum - v;
    const int base = sbase;
    if (tid < node_n) offs[nb0 + tid] = base + excl;
    if (b == NB - 1 && tid == 0) offs[NN] = NE;
    lcnt[tid] = 0;
    loff[tid] = excl;
    __syncthreads();
    for (int i = tid; i < ecnt; i += 1024) {
        int e = ebuf[e0 + i];
        int d = e & 1023;
        int slot = base + loff[d] + atomicAdd(&lcnt[d], 1);
        csr[slot] = e >> 10;
    }
}

// ------- agg: vectorized CSR gather-mean, 2 nodes per wave (32 lanes each) -------
// lane l: half = l>>5 (node select), g = (l&31)>>3 (4 neighbor slots), d8 = l&7.
// Per step each half covers 4 neighbors x full 128B row; shuffle reduce xor 8,16
// stays within the 32-lane half.
__global__ __launch_bounds__(256) void k_aggv(const ushort* __restrict__ xb,
                                              const int* __restrict__ offs,
                                              const int* __restrict__ csr,
                                              ushort* __restrict__ aggb16) {
    int l = threadIdx.x & 63;
    int wave = (blockIdx.x * 256 + threadIdx.x) >> 6;
    int half = l >> 5;
    int wid = wave * 2 + half;  // node
    if (wid >= NN) return;
    int ll = l & 31;
    const int g = ll >> 3, d8 = ll & 7;
    int beg = offs[wid];
    int deg = offs[wid + 1] - beg;
    float a[8] = {0, 0, 0, 0, 0, 0, 0, 0};
    for (int ch = 0; ch < deg; ch += 4) {
        int j = ch + g;
        if (j < deg) {
            int sv = csr[beg + j];
            short8 v = *(const short8*)&xb[(size_t)sv * DIN + d8 * 8];
#pragma unroll
            for (int i = 0; i < 8; ++i) a[i] += b2f(v[i]);
        }
    }
#pragma unroll
    for (int i = 0; i < 8; ++i) {
        a[i] += __shfl_xor(a[i], 8);
        a[i] += __shfl_xor(a[i], 16);
    }
    if (g == 0) {  // 8 lanes per half write 16B each -> 128B contiguous row
        float inv = 1.f / fmaxf((float)deg, 1.f);
        ushort o[8];
#pragma unroll
        for (int i = 0; i < 8; ++i) {
            __hip_bfloat16 b = __float2bfloat16(a[i] * inv);
            o[i] = *(ushort*)&b;
        }
        *(uint4*)&aggb16[(size_t)wid * DIN + d8 * 8] = *(uint4*)o;
    }
}

// ---------------- MFMA dual-GEMM: hb = bf16([agg|x] @ [W1l;W1r] + b1), BN partials ----
__global__ __launch_bounds__(256, 4) void k_mmx(const ushort* __restrict__ aggb16,
                                                const ushort* __restrict__ xb,
                                                const ushort* __restrict__ wfrag,
                                                const float* __restrict__ b1,
                                                ushort* __restrict__ hb,
                                                float* __restrict__ bnsum,
                                                float* __restrict__ bnsq) {
    __shared__ ushort sA[64 * 136];  // 17 KB, padded stride 136
    const int tid = threadIdx.x;
    const int l = tid & 63, w = tid >> 6;
    const int r0 = l & 15, kg = l >> 4;

    short8 bf[2][4];
#pragma unroll
    for (int c = 0; c < 2; ++c)
#pragma unroll
        for (int ks = 0; ks < 4; ++ks)
            bf[c][ks] = *(const short8*)&wfrag[(((2 * w + c) * 4 + ks) * 64 + l) * 8];

    float bias2[2];
    bias2[0] = b1[(2 * w) * 16 + r0];
    bias2[1] = b1[(2 * w + 1) * 16 + r0];

    float psum2[2] = {0.f, 0.f}, psq2[2] = {0.f, 0.f};

    for (int tile = blockIdx.x; tile < NTILES; tile += gridDim.x) {
        const int tb = tile * 64;
        __syncthreads();  // prior-iter sA readers done
#pragma unroll
        for (int i = 0; i < 4; ++i) {
            int f = tid + i * 256;  // 0..1023 16B-chunks
            int row = f >> 4, ch = f & 15;
            const uint4* src = (ch < 8)
                ? (const uint4*)(aggb16 + (size_t)(tb + row) * 64 + ch * 8)
                : (const uint4*)(xb + (size_t)(tb + row) * 64 + (ch - 8) * 8);
            *(uint4*)&sA[row * 136 + ch * 8] = *src;
        }
        __syncthreads();

#pragma unroll
        for (int s = 0; s < 4; ++s) {
            short8 af[4];
            const int abase = (s * 16 + r0) * 136 + kg * 8;
#pragma unroll
            for (int ks = 0; ks < 4; ++ks)
                af[ks] = *(const short8*)&sA[abase + ks * 32];
#pragma unroll
            for (int c = 0; c < 2; ++c) {
                floatx4 acc = {0.f, 0.f, 0.f, 0.f};
#pragma unroll
                for (int ks = 0; ks < 4; ++ks)
                    acc = __builtin_amdgcn_mfma_f32_16x16x32_bf16(af[ks], bf[c][ks], acc, 0, 0, 0);
                const int col = (2 * w + c) * 16 + r0;
#pragma unroll
                for (int i = 0; i < 4; ++i) {
                    int r = tb + s * 16 + kg * 4 + i;
                    if (r < NN) {
                        float o = acc[i] + bias2[c];
                        __hip_bfloat16 ob = __float2bfloat16(o);
                        hb[(size_t)r * DH + col] = *(ushort*)&ob;
                        psum2[c] += o;
                        psq2[c] += o * o;
                    }
                }
            }
        }
    }

#pragma unroll
    for (int c = 0; c < 2; ++c) {
        float s = psum2[c], q = psq2[c];
        s += __shfl_xor(s, 16); s += __shfl_xor(s, 32);
        q += __shfl_xor(q, 16); q += __shfl_xor(q, 32);
        if (kg == 0) {  // lanes 0..15, channels disjoint across waves
            atomicAdd(&bnsum[(2 * w + c) * 16 + r0], s);
            atomicAdd(&bnsq[(2 * w + c) * 16 + r0], q);
        }
    }
}

// ---------------- per-node projection (BN affine computed per-block in LDS) ----------------
__global__ __launch_bounds__(256) void k_proj(const ushort* __restrict__ hb,
                                              const float* __restrict__ bnsum,
                                              const float* __restrict__ bnsq,
                                              const float* __restrict__ gamma,
                                              const float* __restrict__ beta,
                                              const float* __restrict__ W2l,
                                              const float* __restrict__ W2r,
                                              float4* __restrict__ plr) {
    __shared__ float sCA[DH], sCC[DH];
    int tid = threadIdx.x;
    if (tid < DH) {
        float mu = bnsum[tid] * (1.f / NN);
        float var = bnsq[tid] * (1.f / NN) - mu * mu;
        float a = rsqrtf(var + 1e-5f) * gamma[tid];
        sCA[tid] = a;
        sCC[tid] = beta[tid] - mu * a;
    }
    __syncthreads();
    int wid = (blockIdx.x * 256 + tid) >> 6;  // node
    int lane = tid & 63;
    if (wid >= NN) return;
    int c0 = lane * 2;
    uint hv = *(const uint*)&hb[(size_t)wid * DH + c0];
    float h0 = b2f((short)(hv & 0xffff));
    float h1 = b2f((short)(hv >> 16));
    float hb0 = fmaxf(h0 * sCA[c0] + sCC[c0], 0.f);
    float hb1 = fmaxf(h1 * sCA[c0 + 1] + sCC[c0 + 1], 0.f);
    float pl0 = hb0 * W2l[c0 * 2 + 0] + hb1 * W2l[c0 * 2 + 2];
    float pl1 = hb0 * W2l[c0 * 2 + 1] + hb1 * W2l[c0 * 2 + 3];
    float pr0 = hb0 * W2r[c0 * 2 + 0] + hb1 * W2r[c0 * 2 + 2];
    float pr1 = hb0 * W2r[c0 * 2 + 1] + hb1 * W2r[c0 * 2 + 3];
#pragma unroll
    for (int off = 32; off > 0; off >>= 1) {
        pl0 += __shfl_down(pl0, off);
        pl1 += __shfl_down(pl1, off);
        pr0 += __shfl_down(pr0, off);
        pr1 += __shfl_down(pr1, off);
    }
    if (lane == 0) plr[wid] = make_float4(pl0, pl1, pr0, pr1);
}

// ---------------- layer-2 aggregate + output (4-way unrolled gather) ----------------
__global__ __launch_bounds__(256) void k_out(const float4* __restrict__ plr,
                                             const int* __restrict__ offs,
                                             const int* __restrict__ csr,
                                             const float* __restrict__ b2,
                                             float* __restrict__ out) {
    int d = blockIdx.x * 256 + threadIdx.x;
    if (d >= NN) return;
    int beg = offs[d];
    int deg = offs[d + 1] - beg;
    const float2* pl2 = (const float2*)plr;
    float s0 = 0.f, s1 = 0.f;
    int i = 0;
    for (; i + 4 <= deg; i += 4) {
        int n0 = csr[beg + i], n1 = csr[beg + i + 1];
        int n2 = csr[beg + i + 2], n3 = csr[beg + i + 3];
        float2 p0 = pl2[(size_t)n0 * 2];
        float2 p1 = pl2[(size_t)n1 * 2];
        float2 p2 = pl2[(size_t)n2 * 2];
        float2 p3 = pl2[(size_t)n3 * 2];
        s0 += (p0.x + p1.x) + (p2.x + p3.x);
        s1 += (p0.y + p1.y) + (p2.y + p3.y);
    }
    for (; i < deg; ++i) {
        float2 p = pl2[(size_t)csr[beg + i] * 2];
        s0 += p.x;
        s1 += p.y;
    }
    float inv = 1.f / fmaxf((float)deg, 1.f);
    float4 me = plr[d];
    out[(size_t)d * 2 + 0] = s0 * inv + me.z + b2[0];
    out[(size_t)d * 2 + 1] = s1 * inv + me.w + b2[1];
}

extern "C" void kernel_launch(void* const* d_in, const int* in_sizes, int n_in,
                              void* d_out, int out_size, void* d_ws, size_t ws_size,
                              hipStream_t stream) {
    const float* x = (const float*)d_in[0];
    const int* ei = (const int*)d_in[1];
    const float* W1l = (const float*)d_in[2];
    const float* W1r = (const float*)d_in[3];
    const float* b1 = (const float*)d_in[4];
    const float* gamma = (const float*)d_in[5];
    const float* beta = (const float*)d_in[6];
    const float* W2l = (const float*)d_in[7];
    const float* W2r = (const float*)d_in[8];
    const float* b2 = (const float*)d_in[9];
    float* out = (float*)d_out;
    float* ws = (float*)d_ws;
    int* wsi = (int*)d_ws;

    const int* src = ei;
    const int* dst = ei + NE;

    float* bnsum = ws + OFF_BN;
    float* bnsq = ws + OFF_BN + 128;
    int* gcur = wsi + OFF_GCUR;
    int* offs = wsi + OFF_OFFS;
    int* csr = wsi + OFF_CSR;
    float4* plr = (float4*)(ws + OFF_PLR);
    ushort* wfrag = (ushort*)(ws + OFF_WF);
    ushort* aggb16 = (ushort*)(ws + OFF_AGB);
    ushort* xb = (ushort*)(ws + OFF_XB);
    ushort* hb = (ushort*)(ws + OFF_H);
    int* ebuf = (int*)(ws + OFF_H);  // overlays hb (dead before hb is written)

    // zero bn partials (256) + gcur (98) in one small memset (adjacent in layout)
    hipMemsetAsync(ws, 0, (256 + NB) * sizeof(float), stream);

    k_bucketprep<<<EDGEB + CVTB, 256, 0, stream>>>(x, W1l, W1r, src, dst, xb, wfrag, gcur, ebuf);
    k_place<<<NB, 1024, 0, stream>>>(ebuf, gcur, offs, csr);
    k_aggv<<<(NN * 32 + 255) / 256, 256, 0, stream>>>(xb, offs, csr, aggb16);
    k_mmx<<<782, 256, 0, stream>>>(aggb16, xb, wfrag, b1, hb, bnsum, bnsq);
    k_proj<<<(NN + 3) / 4, 256, 0, stream>>>(hb, bnsum, bnsq, gamma, beta, W2l, W2r, plr);
    k_out<<<(NN + 255) / 256, 256, 0, stream>>>(plr, offs, csr, b2, out);
}